// Round 4
// baseline (1938.429 us; speedup 1.0000x reference)
//
#include <hip/hip_runtime.h>
#include <math.h>

#define NB 256
#define NT 128
#define NDW 300
#define NH 128
#define NTYPE 8
#define NLEVEL 13
#define NN (NB*NT)

#define NBK 117       // 13 node buckets + 104 edge buckets
#define CBLOCKS 64
#define PBLOCKS 256
#define PTHREADS 512
#define PWAVES 8
#define TOTWAVES (PBLOCKS*PWAVES)

// ib layout (ints), at byte offset 32MB of d_ws
#define BC 0                    // [CBLOCKS][NBK] per-block counts
#define BB 8192                 // [CBLOCKS][NBK] per-block base offsets
#define OFF_N 16384             // [14] node-level starts
#define OFF_E 16400             // [105] edge (level,type) starts
#define NODE_LIST 16512
#define EDGE_LIST (16512+NN)

__global__ __launch_bounds__(256) void count_kernel(const int* __restrict__ parent,
    const int* __restrict__ dep_type, const int* __restrict__ height, int* ib) {
  __shared__ int cnt[NBK];
  for (int u = threadIdx.x; u < NBK; u += 256) cnt[u] = 0;
  __syncthreads();
  for (int i = blockIdx.x*256 + threadIdx.x; i < NN; i += CBLOCKS*256) {
    atomicAdd(&cnt[height[i]], 1);
    int p = parent[i];
    if (p >= 0) {
      int gp = (i & ~(NT-1)) + p;
      atomicAdd(&cnt[13 + height[gp]*NTYPE + dep_type[i]], 1);
    }
  }
  __syncthreads();
  for (int u = threadIdx.x; u < NBK; u += 256)
    ib[BC + blockIdx.x*NBK + u] = cnt[u];
}

__global__ __launch_bounds__(128) void scan_kernel(int* ib) {
  __shared__ int total[NBK], start[NBK];
  int u = threadIdx.x;
  if (u < NBK) {
    int acc = 0;
    for (int b = 0; b < CBLOCKS; b++) {
      ib[BB + b*NBK + u] = acc;
      acc += ib[BC + b*NBK + u];
    }
    total[u] = acc;
  }
  __syncthreads();
  if (u == 0) {
    int acc = 0;
    for (int k = 0; k < 13; k++) { start[k] = acc; ib[OFF_N+k] = acc; acc += total[k]; }
    ib[OFF_N+13] = acc;
    acc = 0;
    for (int e = 0; e < 104; e++) { start[13+e] = acc; ib[OFF_E+e] = acc; acc += total[13+e]; }
    ib[OFF_E+104] = acc;
  }
  __syncthreads();
  if (u < NBK) {
    int s = start[u];
    for (int b = 0; b < CBLOCKS; b++) ib[BB + b*NBK + u] += s;
  }
}

__global__ __launch_bounds__(256) void scatter_kernel(const int* __restrict__ parent,
    const int* __restrict__ dep_type, const int* __restrict__ height, int* ib) {
  __shared__ int base[NBK];
  __shared__ int cnt[NBK];
  for (int u = threadIdx.x; u < NBK; u += 256) {
    base[u] = ib[BB + blockIdx.x*NBK + u];
    cnt[u] = 0;
  }
  __syncthreads();
  for (int i = blockIdx.x*256 + threadIdx.x; i < NN; i += CBLOCKS*256) {
    int hb = height[i];
    int pos = atomicAdd(&cnt[hb], 1);
    ib[NODE_LIST + base[hb] + pos] = i;
    int p = parent[i];
    if (p >= 0) {
      int gp = (i & ~(NT-1)) + p;
      int eb = 13 + height[gp]*NTYPE + dep_type[i];
      int pe = atomicAdd(&cnt[eb], 1);
      ib[EDGE_LIST + base[eb] + pe] = i;
    }
  }
}

// wx = token_emb @ W_wh.T ; also zero hbuf (seg accumulator / output)  [R2 version]
__global__ __launch_bounds__(128) void wx_kernel(const float* __restrict__ x,
    const float* __restrict__ Wwh, float* __restrict__ wx, float* __restrict__ hbuf) {
  __shared__ float sx[32][NDW];
  int block_row = blockIdx.x * 32;
  int tid = threadIdx.x;
  for (int idx = tid; idx < 32*NDW; idx += 128) {
    int r = idx / NDW, d = idx - r*NDW;
    sx[r][d] = x[(size_t)(block_row + r)*NDW + d];
  }
  __syncthreads();
  const float* wrow = Wwh + (size_t)tid*NDW;
  float acc[32];
  #pragma unroll
  for (int r = 0; r < 32; r++) acc[r] = 0.f;
  for (int d = 0; d < NDW; d++) {
    float w = wrow[d];
    #pragma unroll
    for (int r = 0; r < 32; r++) acc[r] += w * sx[r][d];
  }
  for (int r = 0; r < 32; r++) {
    wx[(size_t)(block_row+r)*NH + tid] = acc[r];
    hbuf[(size_t)(block_row+r)*NH + tid] = 0.f;
  }
}

// ---------------- persistent cooperative level engine ----------------

__device__ __forceinline__ void grid_barrier(int* bar) {
  __syncthreads();
  if (threadIdx.x == 0) {
    __threadfence();
    int gen = __hip_atomic_load(&bar[1], __ATOMIC_ACQUIRE, __HIP_MEMORY_SCOPE_AGENT);
    if (__hip_atomic_fetch_add(&bar[0], 1, __ATOMIC_ACQ_REL, __HIP_MEMORY_SCOPE_AGENT)
        == PBLOCKS-1) {
      __hip_atomic_store(&bar[0], 0, __ATOMIC_RELAXED, __HIP_MEMORY_SCOPE_AGENT);
      __hip_atomic_fetch_add(&bar[1], 1, __ATOMIC_RELEASE, __HIP_MEMORY_SCOPE_AGENT);
    } else {
      while (__hip_atomic_load(&bar[1], __ATOMIC_ACQUIRE, __HIP_MEMORY_SCOPE_AGENT) == gen)
        __builtin_amdgcn_s_sleep(8);
    }
  }
  __syncthreads();
}

__device__ __forceinline__ void stageW(const float* __restrict__ W, float* sW, int tid) {
  for (int idx = tid; idx < 128*32; idx += PTHREADS) {
    int r = idx >> 5, c = idx & 31;
    *(float4*)&sW[r*132 + c*4] = *(const float4*)&W[r*128 + c*4];
  }
}

__device__ __forceinline__ void matvec8(const float* sW, const float (*sv)[NH],
                                        int lane, float* o0, float* o1) {
  #pragma unroll
  for (int j = 0; j < 8; j++) { o0[j] = 0.f; o1[j] = 0.f; }
  #pragma unroll 4
  for (int d4 = 0; d4 < 32; d4++) {
    float4 w0 = *(const float4*)&sW[lane*132 + d4*4];
    float4 w1 = *(const float4*)&sW[(lane+64)*132 + d4*4];
    #pragma unroll
    for (int j = 0; j < 8; j++) {
      float4 v = *(const float4*)&sv[j][d4*4];
      o0[j] += w0.x*v.x + w0.y*v.y + w0.z*v.z + w0.w*v.w;
      o1[j] += w1.x*v.x + w1.y*v.y + w1.z*v.z + w1.w*v.w;
    }
  }
}

__global__ __launch_bounds__(PTHREADS, 2) void level_kernel(
    const float* __restrict__ Whr, const float* __restrict__ Wrel,
    const float* __restrict__ bwh, const float* __restrict__ wx,
    const int* __restrict__ parent, const int* __restrict__ ib,
    float* __restrict__ hbuf, float* __restrict__ g, int* bar) {
  __shared__ __align__(16) float sW[128*132];        // 67.6 KB, shared by both phases
  __shared__ __align__(16) float sh[PWAVES][8][NH];  // 32 KB
  int tid = threadIdx.x;
  int wave = tid >> 6, lane = tid & 63;
  int bid = blockIdx.x;
  int role = bid & 7;          // W_rel type for edge phases
  int sub  = bid >> 3;         // 0..31 within type
  float b0 = bwh[lane], b1 = bwh[64+lane];

  for (int k = 0; k < NLEVEL; k++) {
    // ---------- edge phase (k>=1): parents at height k ----------
    if (k > 0) {
      int bs = ib[OFF_E + k*NTYPE + role];
      int be = ib[OFF_E + k*NTYPE + role + 1];
      int nbat = (be - bs + 7) >> 3;
      if (sub*PWAVES < nbat) {
        stageW(Wrel + (size_t)role*NH*NH, sW, tid);
        __syncthreads();
        for (int b = sub*PWAVES + wave; b < nbat; b += 32*PWAVES) {
          int base = bs + b*8;
          int cnt = be - base; if (cnt > 8) cnt = 8;
          int pidx[8];
          #pragma unroll
          for (int j = 0; j < 8; j++) {
            int it = base + j; if (it >= be) it = be - 1;   // clamp tail (wave-uniform)
            int c = ib[EDGE_LIST + it];
            int p = (c & ~(NT-1)) + parent[c];
            pidx[j] = p;
            float r0 = tanhf(g[(size_t)c*NH + lane]      + wx[(size_t)p*NH + lane]);
            float r1 = tanhf(g[(size_t)c*NH + 64 + lane] + wx[(size_t)p*NH + 64 + lane]);
            sh[wave][j][lane] = r0; sh[wave][j][64+lane] = r1;  // wave-synchronous LDS
          }
          float o0[8], o1[8];
          matvec8(sW, sh[wave], lane, o0, o1);
          #pragma unroll
          for (int j = 0; j < 8; j++) if (j < cnt) {
            atomicAdd(&hbuf[(size_t)pidx[j]*NH + lane],      o0[j]);
            atomicAdd(&hbuf[(size_t)pidx[j]*NH + 64 + lane], o1[j]);
          }
        }
      }
      grid_barrier(bar);
    }
    // ---------- node phase: finalize h at height k, compute g = W_hr @ h ----------
    int ns = ib[OFF_N + k], ne = ib[OFF_N + k + 1];
    int nbat = (ne - ns + 7) >> 3;
    if (bid*PWAVES < nbat) {
      stageW(Whr, sW, tid);
      __syncthreads();
      for (int b = bid*PWAVES + wave; b < nbat; b += TOTWAVES) {
        int base = ns + b*8;
        int cnt = ne - base; if (cnt > 8) cnt = 8;
        int idxs[8];
        #pragma unroll
        for (int j = 0; j < 8; j++) {
          int it = base + j; if (it >= ne) it = ne - 1;     // clamp tail (wave-uniform)
          int i = ib[NODE_LIST + it];
          idxs[j] = i;
          float s0 = tanhf(wx[(size_t)i*NH + lane]      + b0);
          float s1 = tanhf(wx[(size_t)i*NH + 64 + lane] + b1);
          float h0, h1;
          if (k == 0) { h0 = s0; h1 = s1; }
          else {
            h0 = tanhf(hbuf[(size_t)i*NH + lane]      + s0);
            h1 = tanhf(hbuf[(size_t)i*NH + 64 + lane] + s1);
          }
          if (j < cnt) {
            hbuf[(size_t)i*NH + lane]      = h0;
            hbuf[(size_t)i*NH + 64 + lane] = h1;
          }
          sh[wave][j][lane] = h0; sh[wave][j][64+lane] = h1;  // wave-synchronous LDS
        }
        float o0[8], o1[8];
        matvec8(sW, sh[wave], lane, o0, o1);
        #pragma unroll
        for (int j = 0; j < 8; j++) if (j < cnt) {
          g[(size_t)idxs[j]*NH + lane]      = o0[j];
          g[(size_t)idxs[j]*NH + 64 + lane] = o1[j];
        }
      }
    }
    if (k < NLEVEL-1) grid_barrier(bar);
  }
}

extern "C" void kernel_launch(void* const* d_in, const int* in_sizes, int n_in,
                              void* d_out, int out_size, void* d_ws, size_t ws_size,
                              hipStream_t stream) {
  const float* token  = (const float*)d_in[0];
  const float* Wwh    = (const float*)d_in[1];
  const float* bwh    = (const float*)d_in[2];
  const float* Whr    = (const float*)d_in[3];
  const float* Wrel   = (const float*)d_in[4];
  const int*   parent = (const int*)d_in[5];
  const int*   dep    = (const int*)d_in[6];
  const int*   height = (const int*)d_in[7];

  float* hbuf = (float*)d_out;                          // seg-accumulator, then final h
  float* wx   = (float*)d_ws;                           // [NN,NH] f32, 16MB
  float* g    = (float*)((char*)d_ws + 16777216);       // [NN,NH] f32, 16MB
  int*   ib   = (int*)((char*)d_ws + 33554432);         // bucket metadata + lists (~330KB)
  int*   bar  = (int*)((char*)d_ws + 33554432 + 524288);// grid-barrier state

  hipMemsetAsync(bar, 0, 64, stream);
  count_kernel<<<CBLOCKS, 256, 0, stream>>>(parent, dep, height, ib);
  scan_kernel<<<1, 128, 0, stream>>>(ib);
  scatter_kernel<<<CBLOCKS, 256, 0, stream>>>(parent, dep, height, ib);
  wx_kernel<<<NN/32, 128, 0, stream>>>(token, Wwh, wx, hbuf);
  level_kernel<<<PBLOCKS, PTHREADS, 0, stream>>>(Whr, Wrel, bwh, wx, parent, ib, hbuf, g, bar);
}

// Round 5
// 622.640 us; speedup vs baseline: 3.1132x; 3.1132x over previous
//
#include <hip/hip_runtime.h>
#include <math.h>

#define NB 256
#define NT 128
#define NDW 300
#define NH 128
#define NTYPE 8
#define NLEVEL 13
#define NN (NB*NT)

#define NBK 104       // (height 0..12) x (type 0..7) node buckets
#define CBLOCKS 64
#define PWAVES 8

// ib layout (ints), at byte offset 16MB of d_ws
#define BC 0                    // [CBLOCKS][NBK] per-block counts
#define BB 8192                 // [CBLOCKS][NBK] per-block base offsets
#define OFF 16384               // [NBK+1] bucket starts
#define NODE_LIST 16512         // [NN]

__global__ __launch_bounds__(256) void count_kernel(const int* __restrict__ dep_type,
    const int* __restrict__ height, int* ib) {
  __shared__ int cnt[NBK];
  for (int u = threadIdx.x; u < NBK; u += 256) cnt[u] = 0;
  __syncthreads();
  for (int i = blockIdx.x*256 + threadIdx.x; i < NN; i += CBLOCKS*256)
    atomicAdd(&cnt[height[i]*NTYPE + dep_type[i]], 1);
  __syncthreads();
  for (int u = threadIdx.x; u < NBK; u += 256)
    ib[BC + blockIdx.x*NBK + u] = cnt[u];
}

__global__ __launch_bounds__(128) void scan_kernel(int* ib) {
  __shared__ int total[NBK], start[NBK];
  int u = threadIdx.x;
  if (u < NBK) {
    int acc = 0;
    for (int b = 0; b < CBLOCKS; b++) {
      ib[BB + b*NBK + u] = acc;
      acc += ib[BC + b*NBK + u];
    }
    total[u] = acc;
  }
  __syncthreads();
  if (u == 0) {
    int acc = 0;
    for (int e = 0; e < NBK; e++) { start[e] = acc; ib[OFF+e] = acc; acc += total[e]; }
    ib[OFF+NBK] = acc;
  }
  __syncthreads();
  if (u < NBK) {
    int s = start[u];
    for (int b = 0; b < CBLOCKS; b++) ib[BB + b*NBK + u] += s;
  }
}

__global__ __launch_bounds__(256) void scatter_kernel(const int* __restrict__ dep_type,
    const int* __restrict__ height, int* ib) {
  __shared__ int base[NBK];
  __shared__ int cnt[NBK];
  for (int u = threadIdx.x; u < NBK; u += 256) {
    base[u] = ib[BB + blockIdx.x*NBK + u];
    cnt[u] = 0;
  }
  __syncthreads();
  for (int i = blockIdx.x*256 + threadIdx.x; i < NN; i += CBLOCKS*256) {
    int bk = height[i]*NTYPE + dep_type[i];
    int pos = atomicAdd(&cnt[bk], 1);
    ib[NODE_LIST + base[bk] + pos] = i;
  }
}

// wx = token_emb @ W_wh.T ; also zero hbuf (seg accumulator / output)  [proven R2 version]
__global__ __launch_bounds__(128) void wx_kernel(const float* __restrict__ x,
    const float* __restrict__ Wwh, float* __restrict__ wx, float* __restrict__ hbuf) {
  __shared__ float sx[32][NDW];
  int block_row = blockIdx.x * 32;
  int tid = threadIdx.x;
  for (int idx = tid; idx < 32*NDW; idx += 128) {
    int r = idx / NDW, d = idx - r*NDW;
    sx[r][d] = x[(size_t)(block_row + r)*NDW + d];
  }
  __syncthreads();
  const float* wrow = Wwh + (size_t)tid*NDW;
  float acc[32];
  #pragma unroll
  for (int r = 0; r < 32; r++) acc[r] = 0.f;
  for (int d = 0; d < NDW; d++) {
    float w = wrow[d];
    #pragma unroll
    for (int r = 0; r < 32; r++) acc[r] += w * sx[r][d];
  }
  for (int r = 0; r < 32; r++) {
    wx[(size_t)(block_row+r)*NH + tid] = acc[r];
    hbuf[(size_t)(block_row+r)*NH + tid] = 0.f;
  }
}

__device__ __forceinline__ unsigned int pack_bf16(float a, float b) {
  unsigned int ua = __float_as_uint(a); ua += 0x7fff + ((ua >> 16) & 1);
  unsigned int ub = __float_as_uint(b); ub += 0x7fff + ((ub >> 16) & 1);
  return (ua >> 16) | (ub & 0xffff0000u);
}

// Phase k: for nodes i with height==k, bucketed by dep_type t=blockIdx&7:
//   h_i = tanh(hbuf_i + simple_i)   (or simple_i at k==0)   -> write hbuf_i (final)
//   g_i = W_hr . h_i                (registers)
//   r   = tanh(g_i + wx_parent); infl = W_rel[t] . r; atomicAdd -> hbuf[parent]
// W_hr fp32 (64KB) + W_rel[t] bf16 (32KB), both XOR-swizzled (conflict-free, no pad),
// + per-wave 8-node batch vectors (32KB) = 128KB LDS, 1 block/CU, 8 waves.
__global__ __launch_bounds__(512, 2) void phase_kernel(
    const float* __restrict__ Whr, const float* __restrict__ Wrel,
    const float* __restrict__ bwh, const float* __restrict__ wx,
    const int* __restrict__ parent, const int* __restrict__ ib,
    float* __restrict__ hbuf, int k) {
  int t = blockIdx.x & 7, sub = blockIdx.x >> 3;     // 32 subs per type
  int bs = ib[OFF + k*NTYPE + t];
  int be = ib[OFF + k*NTYPE + t + 1];
  int nbat = (be - bs + 7) >> 3;
  if (sub*PWAVES >= nbat) return;                    // uniform early-exit before staging
  __shared__ __align__(16) float sWhr[NH*NH];        // 64 KB
  __shared__ __align__(16) unsigned int sWrel[NH*64];// 32 KB (bf16 pairs)
  __shared__ __align__(16) float sh[PWAVES][8][NH];  // 32 KB
  int tid = threadIdx.x;
  for (int idx = tid; idx < NH*32; idx += 512) {
    int row = idx >> 5, d4 = idx & 31;
    float4 v = *(const float4*)&Whr[(size_t)row*NH + d4*4];
    *(float4*)&sWhr[row*NH + ((d4 ^ (row & 31)) << 2)] = v;
  }
  for (int idx = tid; idx < NH*32; idx += 512) {
    int row = idx >> 5, d4 = idx & 31;
    float4 v = *(const float4*)&Wrel[(size_t)t*NH*NH + (size_t)row*NH + d4*4];
    uint2 u; u.x = pack_bf16(v.x, v.y); u.y = pack_bf16(v.z, v.w);
    *(uint2*)&sWrel[row*64 + ((d4 ^ (row & 31)) << 1)] = u;
  }
  __syncthreads();
  int wave = tid >> 6, lane = tid & 63;
  int sw = lane & 31;                                // same swizzle key for rows lane, lane+64
  const float* wr0 = &sWhr[lane*NH];
  const float* wr1 = &sWhr[(lane+64)*NH];
  const unsigned int* ur0 = &sWrel[lane*64];
  const unsigned int* ur1 = &sWrel[(lane+64)*64];
  float b0 = bwh[lane], b1 = bwh[64+lane];
  for (int b = sub*PWAVES + wave; b < nbat; b += 32*PWAVES) {
    int base = bs + b*8;
    int cnt = be - base; if (cnt > 8) cnt = 8;
    int idxs[8], pidx[8];
    #pragma unroll
    for (int j = 0; j < 8; j++) {
      int it = base + j; if (it >= be) it = be - 1;  // clamp tail (wave-uniform)
      int i = ib[NODE_LIST + it];
      idxs[j] = i;
      float s0 = tanhf(wx[(size_t)i*NH + lane]      + b0);
      float s1 = tanhf(wx[(size_t)i*NH + 64 + lane] + b1);
      float h0, h1;
      if (k == 0) { h0 = s0; h1 = s1; }
      else {
        h0 = tanhf(hbuf[(size_t)i*NH + lane]      + s0);
        h1 = tanhf(hbuf[(size_t)i*NH + 64 + lane] + s1);
      }
      if (j < cnt) {
        hbuf[(size_t)i*NH + lane]      = h0;        // final h for node i
        hbuf[(size_t)i*NH + 64 + lane] = h1;
      }
      sh[wave][j][lane] = h0; sh[wave][j][64+lane] = h1;   // wave-synchronous LDS
      int p = parent[i];
      pidx[j] = (j < cnt && p >= 0) ? (i & ~(NT-1)) + p : -1;
    }
    // matvec1: g = W_hr . h   (fp32, swizzled conflict-free reads)
    float g0[8], g1[8];
    #pragma unroll
    for (int j = 0; j < 8; j++) { g0[j] = 0.f; g1[j] = 0.f; }
    #pragma unroll 4
    for (int d4 = 0; d4 < 32; d4++) {
      float4 w0 = *(const float4*)&wr0[(d4 ^ sw) << 2];
      float4 w1 = *(const float4*)&wr1[(d4 ^ sw) << 2];
      #pragma unroll
      for (int j = 0; j < 8; j++) {
        float4 v = *(const float4*)&sh[wave][j][d4*4];
        g0[j] += w0.x*v.x + w0.y*v.y + w0.z*v.z + w0.w*v.w;
        g1[j] += w1.x*v.x + w1.y*v.y + w1.z*v.z + w1.w*v.w;
      }
    }
    // r = tanh(g + wx_parent) overwrites the wave's batch slots (in-order DS pipe)
    #pragma unroll
    for (int j = 0; j < 8; j++) {
      int p = pidx[j] >= 0 ? pidx[j] : idxs[j];
      float r0 = tanhf(g0[j] + wx[(size_t)p*NH + lane]);
      float r1 = tanhf(g1[j] + wx[(size_t)p*NH + 64 + lane]);
      sh[wave][j][lane] = r0; sh[wave][j][64+lane] = r1;
    }
    // matvec2: infl = W_rel[t] . r   (bf16 weights, unpack via shift/and)
    float o0[8], o1[8];
    #pragma unroll
    for (int j = 0; j < 8; j++) { o0[j] = 0.f; o1[j] = 0.f; }
    #pragma unroll 4
    for (int d4 = 0; d4 < 32; d4++) {
      uint2 u0 = *(const uint2*)&ur0[(d4 ^ sw) << 1];
      uint2 u1 = *(const uint2*)&ur1[(d4 ^ sw) << 1];
      float w00 = __uint_as_float(u0.x << 16), w01 = __uint_as_float(u0.x & 0xffff0000u);
      float w02 = __uint_as_float(u0.y << 16), w03 = __uint_as_float(u0.y & 0xffff0000u);
      float w10 = __uint_as_float(u1.x << 16), w11 = __uint_as_float(u1.x & 0xffff0000u);
      float w12 = __uint_as_float(u1.y << 16), w13 = __uint_as_float(u1.y & 0xffff0000u);
      #pragma unroll
      for (int j = 0; j < 8; j++) {
        float4 v = *(const float4*)&sh[wave][j][d4*4];
        o0[j] += w00*v.x + w01*v.y + w02*v.z + w03*v.w;
        o1[j] += w10*v.x + w11*v.y + w12*v.z + w13*v.w;
      }
    }
    #pragma unroll
    for (int j = 0; j < 8; j++) if (pidx[j] >= 0) {
      atomicAdd(&hbuf[(size_t)pidx[j]*NH + lane],      o0[j]);
      atomicAdd(&hbuf[(size_t)pidx[j]*NH + 64 + lane], o1[j]);
    }
  }
}

extern "C" void kernel_launch(void* const* d_in, const int* in_sizes, int n_in,
                              void* d_out, int out_size, void* d_ws, size_t ws_size,
                              hipStream_t stream) {
  const float* token  = (const float*)d_in[0];
  const float* Wwh    = (const float*)d_in[1];
  const float* bwh    = (const float*)d_in[2];
  const float* Whr    = (const float*)d_in[3];
  const float* Wrel   = (const float*)d_in[4];
  const int*   parent = (const int*)d_in[5];
  const int*   dep    = (const int*)d_in[6];
  const int*   height = (const int*)d_in[7];

  float* hbuf = (float*)d_out;                          // seg-accumulator, then final h
  float* wx   = (float*)d_ws;                           // [NN,NH] f32, 16MB
  int*   ib   = (int*)((char*)d_ws + 16777216);         // bucket metadata + node list

  count_kernel<<<CBLOCKS, 256, 0, stream>>>(dep, height, ib);
  scan_kernel<<<1, 128, 0, stream>>>(ib);
  scatter_kernel<<<CBLOCKS, 256, 0, stream>>>(dep, height, ib);
  wx_kernel<<<NN/32, 128, 0, stream>>>(token, Wwh, wx, hbuf);
  for (int k = 0; k < NLEVEL; k++)
    phase_kernel<<<256, 512, 0, stream>>>(Whr, Wrel, bwh, wx, parent, ib, hbuf, k);
}

// Round 6
// 599.478 us; speedup vs baseline: 3.2335x; 1.0386x over previous
//
#include <hip/hip_runtime.h>
#include <math.h>

#define NB 256
#define NT 128
#define NDW 300
#define NH 128
#define NTYPE 8
#define NLEVEL 13
#define NN (NB*NT)

#define NBK 104       // (height 0..12) x (type 0..7) node buckets
#define CBLOCKS 64
#define PWAVES 8

// ib layout (ints), at byte offset 16MB of d_ws
#define BC 0                    // [CBLOCKS][NBK] per-block counts
#define BB 8192                 // [CBLOCKS][NBK] per-block base offsets
#define OFF 16384               // [NBK+1] bucket starts
#define NODE_LIST 16512         // [NN]

typedef __attribute__((ext_vector_type(8))) short short8;
typedef __attribute__((ext_vector_type(4))) float f32x4;

__global__ __launch_bounds__(256) void count_kernel(const int* __restrict__ dep_type,
    const int* __restrict__ height, int* ib) {
  __shared__ int cnt[NBK];
  for (int u = threadIdx.x; u < NBK; u += 256) cnt[u] = 0;
  __syncthreads();
  for (int i = blockIdx.x*256 + threadIdx.x; i < NN; i += CBLOCKS*256)
    atomicAdd(&cnt[height[i]*NTYPE + dep_type[i]], 1);
  __syncthreads();
  for (int u = threadIdx.x; u < NBK; u += 256)
    ib[BC + blockIdx.x*NBK + u] = cnt[u];
}

__global__ __launch_bounds__(128) void scan_kernel(int* ib) {
  __shared__ int total[NBK], start[NBK];
  int u = threadIdx.x;
  if (u < NBK) {
    int acc = 0;
    for (int b = 0; b < CBLOCKS; b++) {
      ib[BB + b*NBK + u] = acc;
      acc += ib[BC + b*NBK + u];
    }
    total[u] = acc;
  }
  __syncthreads();
  if (u == 0) {
    int acc = 0;
    for (int e = 0; e < NBK; e++) { start[e] = acc; ib[OFF+e] = acc; acc += total[e]; }
    ib[OFF+NBK] = acc;
  }
  __syncthreads();
  if (u < NBK) {
    int s = start[u];
    for (int b = 0; b < CBLOCKS; b++) ib[BB + b*NBK + u] += s;
  }
}

__global__ __launch_bounds__(256) void scatter_kernel(const int* __restrict__ dep_type,
    const int* __restrict__ height, int* ib) {
  __shared__ int base[NBK];
  __shared__ int cnt[NBK];
  for (int u = threadIdx.x; u < NBK; u += 256) {
    base[u] = ib[BB + blockIdx.x*NBK + u];
    cnt[u] = 0;
  }
  __syncthreads();
  for (int i = blockIdx.x*256 + threadIdx.x; i < NN; i += CBLOCKS*256) {
    int bk = height[i]*NTYPE + dep_type[i];
    int pos = atomicAdd(&cnt[bk], 1);
    ib[NODE_LIST + base[bk] + pos] = i;
  }
}

__device__ __forceinline__ unsigned int pack_bf16(float a, float b) {
  unsigned int ua = __float_as_uint(a); ua += 0x7fff + ((ua >> 16) & 1);
  unsigned int ub = __float_as_uint(b); ub += 0x7fff + ((ub >> 16) & 1);
  return (ua >> 16) | (ub & 0xffff0000u);
}

// wx = token_emb @ W_wh.T via MFMA bf16. Tile 64m x 128n, K chunks of 32 (300 padded to 320).
// Block: 256 thr (4 waves); wave w owns rows [w*16, w*16+16). Also zeros hbuf rows.
__global__ __launch_bounds__(256) void wx_kernel(const float* __restrict__ x,
    const float* __restrict__ Wwh, float* __restrict__ wx, float* __restrict__ hbuf) {
  __shared__ __align__(16) unsigned int sA[64*16];    // [row][16 uints] = 32 bf16/row
  __shared__ __align__(16) unsigned int sB[128*16];
  int tid = threadIdx.x;
  int wave = tid >> 6, lane = tid & 63;
  size_t rowbase = (size_t)blockIdx.x * 64;
  f32x4 acc[8];
  #pragma unroll
  for (int ni = 0; ni < 8; ni++) acc[ni] = (f32x4){0.f,0.f,0.f,0.f};
  for (int kc = 0; kc < 320; kc += 32) {
    __syncthreads();
    #pragma unroll
    for (int q = 0; q < 2; q++) {             // stage A: 64 rows x 8 float4
      int flat = tid + q*256; int r = flat >> 3, f4 = flat & 7;
      int k0 = kc + f4*4;
      float4 v = make_float4(0.f,0.f,0.f,0.f);
      if (k0 + 3 < NDW) v = *(const float4*)&x[(rowbase + r)*NDW + k0];
      uint2 u; u.x = pack_bf16(v.x, v.y); u.y = pack_bf16(v.z, v.w);
      *(uint2*)&sA[r*16 + f4*2] = u;
    }
    #pragma unroll
    for (int q = 0; q < 4; q++) {             // stage B: 128 rows x 8 float4
      int flat = tid + q*256; int r = flat >> 3, f4 = flat & 7;
      int k0 = kc + f4*4;
      float4 v = make_float4(0.f,0.f,0.f,0.f);
      if (k0 + 3 < NDW) v = *(const float4*)&Wwh[(size_t)r*NDW + k0];
      uint2 u; u.x = pack_bf16(v.x, v.y); u.y = pack_bf16(v.z, v.w);
      *(uint2*)&sB[r*16 + f4*2] = u;
    }
    __syncthreads();
    short8 a = *(const short8*)&sA[(wave*16 + (lane & 15))*16 + (lane >> 4)*4];
    #pragma unroll
    for (int ni = 0; ni < 8; ni++) {
      short8 b = *(const short8*)&sB[(ni*16 + (lane & 15))*16 + (lane >> 4)*4];
      acc[ni] = __builtin_amdgcn_mfma_f32_16x16x32_bf16(a, b, acc[ni], 0, 0, 0);
    }
  }
  int rbase = wave*16 + (lane >> 4)*4;
  #pragma unroll
  for (int ni = 0; ni < 8; ni++)
    #pragma unroll
    for (int reg = 0; reg < 4; reg++)
      wx[(rowbase + rbase + reg)*NH + ni*16 + (lane & 15)] = acc[ni][reg];
  float4 z = make_float4(0.f,0.f,0.f,0.f);
  #pragma unroll
  for (int q = 0; q < 8; q++) {
    int flat = tid + q*256; int r = flat >> 5, c = flat & 31;
    *(float4*)&hbuf[(rowbase + r)*NH + c*4] = z;
  }
}

// 8-node batched matvec with bf16 LDS weights (uint2 granules, XOR-swizzled)
__device__ __forceinline__ void matvec8_bf16(const unsigned int* ur0,
    const unsigned int* ur1, int swz, const float (*sv)[NH], float* o0, float* o1) {
  #pragma unroll
  for (int j = 0; j < 8; j++) { o0[j] = 0.f; o1[j] = 0.f; }
  #pragma unroll 4
  for (int d4 = 0; d4 < 32; d4++) {
    uint2 u0 = *(const uint2*)&ur0[(d4 ^ swz) << 1];
    uint2 u1 = *(const uint2*)&ur1[(d4 ^ swz) << 1];
    float w00 = __uint_as_float(u0.x << 16), w01 = __uint_as_float(u0.x & 0xffff0000u);
    float w02 = __uint_as_float(u0.y << 16), w03 = __uint_as_float(u0.y & 0xffff0000u);
    float w10 = __uint_as_float(u1.x << 16), w11 = __uint_as_float(u1.x & 0xffff0000u);
    float w12 = __uint_as_float(u1.y << 16), w13 = __uint_as_float(u1.y & 0xffff0000u);
    #pragma unroll
    for (int j = 0; j < 8; j++) {
      float4 v = *(const float4*)&sv[j][d4*4];
      o0[j] += w00*v.x + w01*v.y + w02*v.z + w03*v.w;
      o1[j] += w10*v.x + w11*v.y + w12*v.z + w13*v.w;
    }
  }
}

// Phase k: nodes with height==k, bucketed by dep_type t=blockIdx&7:
//   h_i = tanh(hbuf_i + simple_i)  (simple_i at k==0) -> hbuf_i final
//   g_i = W_hr . h_i ; r = tanh(g_i + wx_parent); infl = W_rel[t] . r -> atomicAdd hbuf[parent]
// W_hr bf16 (32KB) + W_rel[t] bf16 (32KB) + batch vectors (32KB) = 96KB LDS.
__global__ __launch_bounds__(512, 2) void phase_kernel(
    const float* __restrict__ Whr, const float* __restrict__ Wrel,
    const float* __restrict__ bwh, const float* __restrict__ wx,
    const int* __restrict__ parent, const int* __restrict__ ib,
    float* __restrict__ hbuf, int k) {
  int t = blockIdx.x & 7, sub = blockIdx.x >> 3;     // 32 subs per type
  int bs = ib[OFF + k*NTYPE + t];
  int be = ib[OFF + k*NTYPE + t + 1];
  int nbat = (be - bs + 7) >> 3;
  if (sub*PWAVES >= nbat) return;                    // uniform early-exit before staging
  __shared__ __align__(16) unsigned int sWhr[NH*64]; // 32 KB (bf16 pairs)
  __shared__ __align__(16) unsigned int sWrel[NH*64];// 32 KB
  __shared__ __align__(16) float sh[PWAVES][8][NH];  // 32 KB
  int tid = threadIdx.x;
  for (int idx = tid; idx < NH*32; idx += 512) {
    int row = idx >> 5, g = idx & 31;
    float4 v = *(const float4*)&Whr[(size_t)row*NH + g*4];
    uint2 u; u.x = pack_bf16(v.x, v.y); u.y = pack_bf16(v.z, v.w);
    *(uint2*)&sWhr[row*64 + ((g ^ (row & 31)) << 1)] = u;
  }
  for (int idx = tid; idx < NH*32; idx += 512) {
    int row = idx >> 5, g = idx & 31;
    float4 v = *(const float4*)&Wrel[(size_t)t*NH*NH + (size_t)row*NH + g*4];
    uint2 u; u.x = pack_bf16(v.x, v.y); u.y = pack_bf16(v.z, v.w);
    *(uint2*)&sWrel[row*64 + ((g ^ (row & 31)) << 1)] = u;
  }
  __syncthreads();
  int wave = tid >> 6, lane = tid & 63;
  int swz = lane & 31;                               // same key for rows lane, lane+64
  const unsigned int* hr0 = &sWhr[lane*64];
  const unsigned int* hr1 = &sWhr[(lane+64)*64];
  const unsigned int* re0 = &sWrel[lane*64];
  const unsigned int* re1 = &sWrel[(lane+64)*64];
  float b0 = bwh[lane], b1 = bwh[64+lane];
  for (int b = sub*PWAVES + wave; b < nbat; b += 32*PWAVES) {
    int base = bs + b*8;
    int cnt = be - base; if (cnt > 8) cnt = 8;
    int idxs[8], pidx[8];
    #pragma unroll
    for (int j = 0; j < 8; j++) {
      int it = base + j; if (it >= be) it = be - 1;  // clamp tail (wave-uniform)
      int i = ib[NODE_LIST + it];
      idxs[j] = i;
      float s0 = tanhf(wx[(size_t)i*NH + lane]      + b0);
      float s1 = tanhf(wx[(size_t)i*NH + 64 + lane] + b1);
      float h0, h1;
      if (k == 0) { h0 = s0; h1 = s1; }
      else {
        h0 = tanhf(hbuf[(size_t)i*NH + lane]      + s0);
        h1 = tanhf(hbuf[(size_t)i*NH + 64 + lane] + s1);
      }
      if (j < cnt) {
        hbuf[(size_t)i*NH + lane]      = h0;        // final h for node i
        hbuf[(size_t)i*NH + 64 + lane] = h1;
      }
      sh[wave][j][lane] = h0; sh[wave][j][64+lane] = h1;   // wave-synchronous LDS
      int p = parent[i];
      pidx[j] = (j < cnt && p >= 0) ? (i & ~(NT-1)) + p : -1;
    }
    float g0[8], g1[8];
    matvec8_bf16(hr0, hr1, swz, sh[wave], g0, g1);   // g = W_hr . h
    #pragma unroll
    for (int j = 0; j < 8; j++) {                    // r = tanh(g + wx_parent)
      int p = pidx[j] >= 0 ? pidx[j] : idxs[j];
      float r0 = tanhf(g0[j] + wx[(size_t)p*NH + lane]);
      float r1 = tanhf(g1[j] + wx[(size_t)p*NH + 64 + lane]);
      sh[wave][j][lane] = r0; sh[wave][j][64+lane] = r1;
    }
    float o0[8], o1[8];
    matvec8_bf16(re0, re1, swz, sh[wave], o0, o1);   // infl = W_rel[t] . r
    #pragma unroll
    for (int j = 0; j < 8; j++) if (pidx[j] >= 0) {
      atomicAdd(&hbuf[(size_t)pidx[j]*NH + lane],      o0[j]);
      atomicAdd(&hbuf[(size_t)pidx[j]*NH + 64 + lane], o1[j]);
    }
  }
}

extern "C" void kernel_launch(void* const* d_in, const int* in_sizes, int n_in,
                              void* d_out, int out_size, void* d_ws, size_t ws_size,
                              hipStream_t stream) {
  const float* token  = (const float*)d_in[0];
  const float* Wwh    = (const float*)d_in[1];
  const float* bwh    = (const float*)d_in[2];
  const float* Whr    = (const float*)d_in[3];
  const float* Wrel   = (const float*)d_in[4];
  const int*   parent = (const int*)d_in[5];
  const int*   dep    = (const int*)d_in[6];
  const int*   height = (const int*)d_in[7];

  float* hbuf = (float*)d_out;                          // seg-accumulator, then final h
  float* wx   = (float*)d_ws;                           // [NN,NH] f32, 16MB
  int*   ib   = (int*)((char*)d_ws + 16777216);         // bucket metadata + node list

  count_kernel<<<CBLOCKS, 256, 0, stream>>>(dep, height, ib);
  scan_kernel<<<1, 128, 0, stream>>>(ib);
  scatter_kernel<<<CBLOCKS, 256, 0, stream>>>(dep, height, ib);
  wx_kernel<<<NN/64, 256, 0, stream>>>(token, Wwh, wx, hbuf);
  for (int k = 0; k < NLEVEL; k++)
    phase_kernel<<<256, 512, 0, stream>>>(Whr, Wrel, bwh, wx, parent, ib, hbuf, k);
}

// Round 7
// 448.608 us; speedup vs baseline: 4.3210x; 1.3363x over previous
//
#include <hip/hip_runtime.h>
#include <math.h>

#define NB 256
#define NT 128
#define NDW 300
#define NH 128
#define NTYPE 8
#define NLEVEL 13
#define NN (NB*NT)

#define NBK 104       // (height 0..12) x (type 0..7) node buckets
#define CBLOCKS 64
#define PBLOCKS 1024  // phase grid: 128 subs per type x 8 types

// ib layout (ints), at byte offset 16MB of d_ws
#define BC 0                    // [CBLOCKS][NBK] per-block counts
#define BB 8192                 // [CBLOCKS][NBK] per-block base offsets
#define OFF 16384               // [NBK+1] bucket starts
#define NODE_LIST 16512         // [NN]

typedef __attribute__((ext_vector_type(8))) short short8;
typedef __attribute__((ext_vector_type(4))) float f32x4;

__global__ __launch_bounds__(256) void count_kernel(const int* __restrict__ dep_type,
    const int* __restrict__ height, int* ib) {
  __shared__ int cnt[NBK];
  for (int u = threadIdx.x; u < NBK; u += 256) cnt[u] = 0;
  __syncthreads();
  for (int i = blockIdx.x*256 + threadIdx.x; i < NN; i += CBLOCKS*256)
    atomicAdd(&cnt[height[i]*NTYPE + dep_type[i]], 1);
  __syncthreads();
  for (int u = threadIdx.x; u < NBK; u += 256)
    ib[BC + blockIdx.x*NBK + u] = cnt[u];
}

__global__ __launch_bounds__(128) void scan_kernel(int* ib) {
  __shared__ int total[NBK], start[NBK];
  int u = threadIdx.x;
  if (u < NBK) {
    int acc = 0;
    for (int b = 0; b < CBLOCKS; b++) {
      ib[BB + b*NBK + u] = acc;
      acc += ib[BC + b*NBK + u];
    }
    total[u] = acc;
  }
  __syncthreads();
  if (u == 0) {
    int acc = 0;
    for (int e = 0; e < NBK; e++) { start[e] = acc; ib[OFF+e] = acc; acc += total[e]; }
    ib[OFF+NBK] = acc;
  }
  __syncthreads();
  if (u < NBK) {
    int s = start[u];
    for (int b = 0; b < CBLOCKS; b++) ib[BB + b*NBK + u] += s;
  }
}

__global__ __launch_bounds__(256) void scatter_kernel(const int* __restrict__ dep_type,
    const int* __restrict__ height, int* ib) {
  __shared__ int base[NBK];
  __shared__ int cnt[NBK];
  for (int u = threadIdx.x; u < NBK; u += 256) {
    base[u] = ib[BB + blockIdx.x*NBK + u];
    cnt[u] = 0;
  }
  __syncthreads();
  for (int i = blockIdx.x*256 + threadIdx.x; i < NN; i += CBLOCKS*256) {
    int bk = height[i]*NTYPE + dep_type[i];
    int pos = atomicAdd(&cnt[bk], 1);
    ib[NODE_LIST + base[bk] + pos] = i;
  }
}

__device__ __forceinline__ unsigned int pack_bf16(float a, float b) {
  unsigned int ua = __float_as_uint(a); ua += 0x7fff + ((ua >> 16) & 1);
  unsigned int ub = __float_as_uint(b); ub += 0x7fff + ((ub >> 16) & 1);
  return (ua >> 16) | (ub & 0xffff0000u);
}

// fast tanh: 1 - 2*rcp(e^{2x}+1); exact at +/-inf, ~1e-6 abs error
__device__ __forceinline__ float ftanh(float x) {
  float e = __expf(2.0f * x);
  return 1.0f - 2.0f * __builtin_amdgcn_rcpf(e + 1.0f);
}

// wx = token_emb @ W_wh.T via MFMA bf16. Tile 64m x 128n, K chunks of 32 (300 pad 320).
__global__ __launch_bounds__(256) void wx_kernel(const float* __restrict__ x,
    const float* __restrict__ Wwh, float* __restrict__ wx, float* __restrict__ hbuf) {
  __shared__ __align__(16) unsigned int sA[64*16];    // [row][16 uints] = 32 bf16/row
  __shared__ __align__(16) unsigned int sB[128*16];
  int tid = threadIdx.x;
  int wave = tid >> 6, lane = tid & 63;
  size_t rowbase = (size_t)blockIdx.x * 64;
  f32x4 acc[8];
  #pragma unroll
  for (int ni = 0; ni < 8; ni++) acc[ni] = (f32x4){0.f,0.f,0.f,0.f};
  for (int kc = 0; kc < 320; kc += 32) {
    __syncthreads();
    #pragma unroll
    for (int q = 0; q < 2; q++) {             // stage A: 64 rows x 8 float4
      int flat = tid + q*256; int r = flat >> 3, f4 = flat & 7;
      int k0 = kc + f4*4;
      float4 v = make_float4(0.f,0.f,0.f,0.f);
      if (k0 + 3 < NDW) v = *(const float4*)&x[(rowbase + r)*NDW + k0];
      uint2 u; u.x = pack_bf16(v.x, v.y); u.y = pack_bf16(v.z, v.w);
      *(uint2*)&sA[r*16 + f4*2] = u;
    }
    #pragma unroll
    for (int q = 0; q < 4; q++) {             // stage B: 128 rows x 8 float4
      int flat = tid + q*256; int r = flat >> 3, f4 = flat & 7;
      int k0 = kc + f4*4;
      float4 v = make_float4(0.f,0.f,0.f,0.f);
      if (k0 + 3 < NDW) v = *(const float4*)&Wwh[(size_t)r*NDW + k0];
      uint2 u; u.x = pack_bf16(v.x, v.y); u.y = pack_bf16(v.z, v.w);
      *(uint2*)&sB[r*16 + f4*2] = u;
    }
    __syncthreads();
    short8 a = *(const short8*)&sA[(wave*16 + (lane & 15))*16 + (lane >> 4)*4];
    #pragma unroll
    for (int ni = 0; ni < 8; ni++) {
      short8 b = *(const short8*)&sB[(ni*16 + (lane & 15))*16 + (lane >> 4)*4];
      acc[ni] = __builtin_amdgcn_mfma_f32_16x16x32_bf16(a, b, acc[ni], 0, 0, 0);
    }
  }
  int rbase = wave*16 + (lane >> 4)*4;
  #pragma unroll
  for (int ni = 0; ni < 8; ni++)
    #pragma unroll
    for (int reg = 0; reg < 4; reg++)
      wx[(rowbase + rbase + reg)*NH + ni*16 + (lane & 15)] = acc[ni][reg];
  float4 z = make_float4(0.f,0.f,0.f,0.f);
  #pragma unroll
  for (int q = 0; q < 8; q++) {
    int flat = tid + q*256; int r = flat >> 5, c = flat & 31;
    *(float4*)&hbuf[(rowbase + r)*NH + c*4] = z;
  }
}

// 8-node batched matvec; weight rows streamed from global (L1/L2-resident fp32)
__device__ __forceinline__ void matvec8_g(const float* __restrict__ w0p,
    const float* __restrict__ w1p, const float (*sv)[NH], float* o0, float* o1) {
  #pragma unroll
  for (int j = 0; j < 8; j++) { o0[j] = 0.f; o1[j] = 0.f; }
  #pragma unroll 4
  for (int d4 = 0; d4 < 32; d4++) {
    float4 w0 = *(const float4*)&w0p[d4*4];
    float4 w1 = *(const float4*)&w1p[d4*4];
    #pragma unroll
    for (int j = 0; j < 8; j++) {
      float4 v = *(const float4*)&sv[j][d4*4];    // wave-uniform: LDS broadcast
      o0[j] += w0.x*v.x + w0.y*v.y + w0.z*v.z + w0.w*v.w;
      o1[j] += w1.x*v.x + w1.y*v.y + w1.z*v.z + w1.w*v.w;
    }
  }
}

// Phase k: nodes with height==k, bucketed by dep_type t=blockIdx&7:
//   h_i = tanh(hbuf_i + simple_i)  (simple_i at k==0) -> hbuf_i final
//   g_i = W_hr.h_i ; r = tanh(g_i + wx_parent); infl = W_rel[t].r -> atomicAdd hbuf[parent]
// LDS = 16KB (batch vectors only); 4 blocks/CU -> 16 waves/CU.
__global__ __launch_bounds__(256, 4) void phase_kernel(
    const float* __restrict__ Whr, const float* __restrict__ Wrel,
    const float* __restrict__ bwh, const float* __restrict__ wx,
    const int* __restrict__ parent, const int* __restrict__ ib,
    float* __restrict__ hbuf, int k) {
  int t = blockIdx.x & 7, sub = blockIdx.x >> 3;     // 128 subs per type
  int bs = ib[OFF + k*NTYPE + t];
  int be = ib[OFF + k*NTYPE + t + 1];
  int nbat = (be - bs + 7) >> 3;
  if (sub*4 >= nbat) return;                         // uniform early-exit (cheap now)
  __shared__ __align__(16) float sh[4][8][NH];       // 16 KB
  int wave = threadIdx.x >> 6, lane = threadIdx.x & 63;
  const float* wr0 = Whr + (size_t)lane*NH;
  const float* wr1 = Whr + (size_t)(lane+64)*NH;
  const float* re0 = Wrel + (size_t)t*NH*NH + (size_t)lane*NH;
  const float* re1 = Wrel + (size_t)t*NH*NH + (size_t)(lane+64)*NH;
  float b0 = bwh[lane], b1 = bwh[64+lane];
  for (int b = sub*4 + wave; b < nbat; b += 128*4) {
    int base = bs + b*8;
    int cnt = be - base; if (cnt > 8) cnt = 8;
    int idxs[8], pidx[8];
    #pragma unroll
    for (int j = 0; j < 8; j++) {
      int it = base + j; if (it >= be) it = be - 1;  // clamp tail (wave-uniform)
      int i = ib[NODE_LIST + it];
      idxs[j] = i;
      float s0 = ftanh(wx[(size_t)i*NH + lane]      + b0);
      float s1 = ftanh(wx[(size_t)i*NH + 64 + lane] + b1);
      float h0, h1;
      if (k == 0) { h0 = s0; h1 = s1; }
      else {
        h0 = ftanh(hbuf[(size_t)i*NH + lane]      + s0);
        h1 = ftanh(hbuf[(size_t)i*NH + 64 + lane] + s1);
      }
      if (j < cnt) {
        hbuf[(size_t)i*NH + lane]      = h0;        // final h for node i
        hbuf[(size_t)i*NH + 64 + lane] = h1;
      }
      sh[wave][j][lane] = h0; sh[wave][j][64+lane] = h1;   // wave-synchronous LDS
      int p = parent[i];
      pidx[j] = (j < cnt && p >= 0) ? (i & ~(NT-1)) + p : -1;
    }
    float g0[8], g1[8];
    matvec8_g(wr0, wr1, sh[wave], g0, g1);           // g = W_hr . h
    #pragma unroll
    for (int j = 0; j < 8; j++) {                    // r = tanh(g + wx_parent)
      int p = pidx[j] >= 0 ? pidx[j] : idxs[j];
      float r0 = ftanh(g0[j] + wx[(size_t)p*NH + lane]);
      float r1 = ftanh(g1[j] + wx[(size_t)p*NH + 64 + lane]);
      sh[wave][j][lane] = r0; sh[wave][j][64+lane] = r1;
    }
    float o0[8], o1[8];
    matvec8_g(re0, re1, sh[wave], o0, o1);           // infl = W_rel[t] . r
    #pragma unroll
    for (int j = 0; j < 8; j++) if (pidx[j] >= 0) {
      atomicAdd(&hbuf[(size_t)pidx[j]*NH + lane],      o0[j]);
      atomicAdd(&hbuf[(size_t)pidx[j]*NH + 64 + lane], o1[j]);
    }
  }
}

extern "C" void kernel_launch(void* const* d_in, const int* in_sizes, int n_in,
                              void* d_out, int out_size, void* d_ws, size_t ws_size,
                              hipStream_t stream) {
  const float* token  = (const float*)d_in[0];
  const float* Wwh    = (const float*)d_in[1];
  const float* bwh    = (const float*)d_in[2];
  const float* Whr    = (const float*)d_in[3];
  const float* Wrel   = (const float*)d_in[4];
  const int*   parent = (const int*)d_in[5];
  const int*   dep    = (const int*)d_in[6];
  const int*   height = (const int*)d_in[7];

  float* hbuf = (float*)d_out;                          // seg-accumulator, then final h
  float* wx   = (float*)d_ws;                           // [NN,NH] f32, 16MB
  int*   ib   = (int*)((char*)d_ws + 16777216);         // bucket metadata + node list

  count_kernel<<<CBLOCKS, 256, 0, stream>>>(dep, height, ib);
  scan_kernel<<<1, 128, 0, stream>>>(ib);
  scatter_kernel<<<CBLOCKS, 256, 0, stream>>>(dep, height, ib);
  wx_kernel<<<NN/64, 256, 0, stream>>>(token, Wwh, wx, hbuf);
  for (int k = 0; k < NLEVEL; k++)
    phase_kernel<<<PBLOCKS, 256, 0, stream>>>(Whr, Wrel, bwh, wx, parent, ib, hbuf, k);
}

// Round 8
// 356.459 us; speedup vs baseline: 5.4380x; 1.2585x over previous
//
#include <hip/hip_runtime.h>
#include <math.h>

#define NB 256
#define NT 128
#define NDW 300
#define NH 128
#define NTYPE 8
#define NLEVEL 13
#define NN (NB*NT)

#define NBK 104       // (height 0..12) x (type 0..7) node buckets
#define CBLOCKS 64
#define PBLOCKS 1024  // phase grid: 128 subs per type x 8 types

// ib layout (ints), at byte offset 16MB of d_ws
#define BC 0                    // [CBLOCKS][NBK] per-block counts
#define BB 8192                 // [CBLOCKS][NBK] per-block base offsets
#define OFF 16384               // [NBK+1] bucket starts
#define NODE_LIST 16512         // [NN]

typedef __attribute__((ext_vector_type(8))) short short8;
typedef __attribute__((ext_vector_type(4))) float f32x4;

__global__ __launch_bounds__(256) void count_kernel(const int* __restrict__ dep_type,
    const int* __restrict__ height, int* ib) {
  __shared__ int cnt[NBK];
  for (int u = threadIdx.x; u < NBK; u += 256) cnt[u] = 0;
  __syncthreads();
  for (int i = blockIdx.x*256 + threadIdx.x; i < NN; i += CBLOCKS*256)
    atomicAdd(&cnt[height[i]*NTYPE + dep_type[i]], 1);
  __syncthreads();
  for (int u = threadIdx.x; u < NBK; u += 256)
    ib[BC + blockIdx.x*NBK + u] = cnt[u];
}

__global__ __launch_bounds__(128) void scan_kernel(int* ib) {
  __shared__ int total[NBK], start[NBK];
  int u = threadIdx.x;
  if (u < NBK) {
    int acc = 0;
    for (int b = 0; b < CBLOCKS; b++) {
      ib[BB + b*NBK + u] = acc;
      acc += ib[BC + b*NBK + u];
    }
    total[u] = acc;
  }
  __syncthreads();
  if (u == 0) {
    int acc = 0;
    for (int e = 0; e < NBK; e++) { start[e] = acc; ib[OFF+e] = acc; acc += total[e]; }
    ib[OFF+NBK] = acc;
  }
  __syncthreads();
  if (u < NBK) {
    int s = start[u];
    for (int b = 0; b < CBLOCKS; b++) ib[BB + b*NBK + u] += s;
  }
}

__global__ __launch_bounds__(256) void scatter_kernel(const int* __restrict__ dep_type,
    const int* __restrict__ height, int* ib) {
  __shared__ int base[NBK];
  __shared__ int cnt[NBK];
  for (int u = threadIdx.x; u < NBK; u += 256) {
    base[u] = ib[BB + blockIdx.x*NBK + u];
    cnt[u] = 0;
  }
  __syncthreads();
  for (int i = blockIdx.x*256 + threadIdx.x; i < NN; i += CBLOCKS*256) {
    int bk = height[i]*NTYPE + dep_type[i];
    int pos = atomicAdd(&cnt[bk], 1);
    ib[NODE_LIST + base[bk] + pos] = i;
  }
}

__device__ __forceinline__ unsigned int pack_bf16(float a, float b) {
  unsigned int ua = __float_as_uint(a); ua += 0x7fff + ((ua >> 16) & 1);
  unsigned int ub = __float_as_uint(b); ub += 0x7fff + ((ub >> 16) & 1);
  return (ua >> 16) | (ub & 0xffff0000u);
}

// fast tanh: 1 - 2*rcp(e^{2x}+1); exact at +/-inf, ~1e-6 abs error
__device__ __forceinline__ float ftanh(float x) {
  float e = __expf(2.0f * x);
  return 1.0f - 2.0f * __builtin_amdgcn_rcpf(e + 1.0f);
}

// wx = token_emb @ W_wh.T via MFMA bf16. Tile 64m x 128n, K chunks of 32 (300 pad 320).
__global__ __launch_bounds__(256) void wx_kernel(const float* __restrict__ x,
    const float* __restrict__ Wwh, float* __restrict__ wx, float* __restrict__ hbuf) {
  __shared__ __align__(16) unsigned int sA[64*16];    // [row][16 uints] = 32 bf16/row
  __shared__ __align__(16) unsigned int sB[128*16];
  int tid = threadIdx.x;
  int wave = tid >> 6, lane = tid & 63;
  size_t rowbase = (size_t)blockIdx.x * 64;
  f32x4 acc[8];
  #pragma unroll
  for (int ni = 0; ni < 8; ni++) acc[ni] = (f32x4){0.f,0.f,0.f,0.f};
  for (int kc = 0; kc < 320; kc += 32) {
    __syncthreads();
    #pragma unroll
    for (int q = 0; q < 2; q++) {             // stage A: 64 rows x 8 float4
      int flat = tid + q*256; int r = flat >> 3, f4 = flat & 7;
      int k0 = kc + f4*4;
      float4 v = make_float4(0.f,0.f,0.f,0.f);
      if (k0 + 3 < NDW) v = *(const float4*)&x[(rowbase + r)*NDW + k0];
      uint2 u; u.x = pack_bf16(v.x, v.y); u.y = pack_bf16(v.z, v.w);
      *(uint2*)&sA[r*16 + f4*2] = u;
    }
    #pragma unroll
    for (int q = 0; q < 4; q++) {             // stage B: 128 rows x 8 float4
      int flat = tid + q*256; int r = flat >> 3, f4 = flat & 7;
      int k0 = kc + f4*4;
      float4 v = make_float4(0.f,0.f,0.f,0.f);
      if (k0 + 3 < NDW) v = *(const float4*)&Wwh[(size_t)r*NDW + k0];
      uint2 u; u.x = pack_bf16(v.x, v.y); u.y = pack_bf16(v.z, v.w);
      *(uint2*)&sB[r*16 + f4*2] = u;
    }
    __syncthreads();
    short8 a = *(const short8*)&sA[(wave*16 + (lane & 15))*16 + (lane >> 4)*4];
    #pragma unroll
    for (int ni = 0; ni < 8; ni++) {
      short8 b = *(const short8*)&sB[(ni*16 + (lane & 15))*16 + (lane >> 4)*4];
      acc[ni] = __builtin_amdgcn_mfma_f32_16x16x32_bf16(a, b, acc[ni], 0, 0, 0);
    }
  }
  int rbase = wave*16 + (lane >> 4)*4;
  #pragma unroll
  for (int ni = 0; ni < 8; ni++)
    #pragma unroll
    for (int reg = 0; reg < 4; reg++)
      wx[(rowbase + rbase + reg)*NH + ni*16 + (lane & 15)] = acc[ni][reg];
  float4 z = make_float4(0.f,0.f,0.f,0.f);
  #pragma unroll
  for (int q = 0; q < 8; q++) {
    int flat = tid + q*256; int r = flat >> 5, c = flat & 31;
    *(float4*)&hbuf[(rowbase + r)*NH + c*4] = z;
  }
}

// 4-node batched matvec; weight rows streamed from global (L1/L2-resident fp32)
__device__ __forceinline__ void matvec4_g(const float* __restrict__ w0p,
    const float* __restrict__ w1p, const float (*sv)[NH], float* o0, float* o1) {
  #pragma unroll
  for (int j = 0; j < 4; j++) { o0[j] = 0.f; o1[j] = 0.f; }
  #pragma unroll 4
  for (int d4 = 0; d4 < 32; d4++) {
    float4 w0 = *(const float4*)&w0p[d4*4];
    float4 w1 = *(const float4*)&w1p[d4*4];
    #pragma unroll
    for (int j = 0; j < 4; j++) {
      float4 v = *(const float4*)&sv[j][d4*4];    // wave-uniform: LDS broadcast
      o0[j] += w0.x*v.x + w0.y*v.y + w0.z*v.z + w0.w*v.w;
      o1[j] += w1.x*v.x + w1.y*v.y + w1.z*v.z + w1.w*v.w;
    }
  }
}

// Phase k: nodes with height==k, bucketed by dep_type t=blockIdx&7:
//   h_i = tanh(hbuf_i + simple_i)  (simple_i at k==0) -> hbuf_i final
//   g_i = W_hr.h_i ; r = tanh(g_i + wx_parent); infl = W_rel[t].r -> atomicAdd hbuf[parent]
// 4 nodes per wave (weight amortization saturates at 4); LDS 8KB; 16 waves/CU.
__global__ __launch_bounds__(256, 4) void phase_kernel(
    const float* __restrict__ Whr, const float* __restrict__ Wrel,
    const float* __restrict__ bwh, const float* __restrict__ wx,
    const int* __restrict__ parent, const int* __restrict__ ib,
    float* __restrict__ hbuf, int k) {
  int t = blockIdx.x & 7, sub = blockIdx.x >> 3;     // 128 subs per type
  int bs = ib[OFF + k*NTYPE + t];
  int be = ib[OFF + k*NTYPE + t + 1];
  int nbat = (be - bs + 3) >> 2;
  if (sub*4 >= nbat) return;                         // uniform early-exit
  __shared__ __align__(16) float sh[4][4][NH];       // 8 KB
  int wave = threadIdx.x >> 6, lane = threadIdx.x & 63;
  const float* wr0 = Whr + (size_t)lane*NH;
  const float* wr1 = Whr + (size_t)(lane+64)*NH;
  const float* re0 = Wrel + (size_t)t*NH*NH + (size_t)lane*NH;
  const float* re1 = Wrel + (size_t)t*NH*NH + (size_t)(lane+64)*NH;
  float b0 = bwh[lane], b1 = bwh[64+lane];
  for (int b = sub*4 + wave; b < nbat; b += 128*4) {
    int base = bs + b*4;
    int cnt = be - base; if (cnt > 4) cnt = 4;
    int idxs[4], pidx[4];
    // pass 1: node indices (wave-uniform -> s_load)
    #pragma unroll
    for (int j = 0; j < 4; j++) {
      int it = base + j; if (it >= be) it = be - 1;  // clamp tail (wave-uniform)
      idxs[j] = ib[NODE_LIST + it];
    }
    // pass 2: all row loads issued back-to-back (max loads in flight)
    float wxv0[4], wxv1[4], hb0[4], hb1[4];
    #pragma unroll
    for (int j = 0; j < 4; j++) {
      wxv0[j] = wx[(size_t)idxs[j]*NH + lane];
      wxv1[j] = wx[(size_t)idxs[j]*NH + 64 + lane];
    }
    if (k > 0) {
      #pragma unroll
      for (int j = 0; j < 4; j++) {
        hb0[j] = hbuf[(size_t)idxs[j]*NH + lane];
        hb1[j] = hbuf[(size_t)idxs[j]*NH + 64 + lane];
      }
    }
    #pragma unroll
    for (int j = 0; j < 4; j++) {
      int p = parent[idxs[j]];
      pidx[j] = (j < cnt && p >= 0) ? (idxs[j] & ~(NT-1)) + p : -1;
    }
    // prefetch parent wx rows early: latency hides under matvec1
    float pw0[4], pw1[4];
    #pragma unroll
    for (int j = 0; j < 4; j++) {
      int p = pidx[j] >= 0 ? pidx[j] : idxs[j];
      pw0[j] = wx[(size_t)p*NH + lane];
      pw1[j] = wx[(size_t)p*NH + 64 + lane];
    }
    // finalize h, publish to LDS + hbuf
    #pragma unroll
    for (int j = 0; j < 4; j++) {
      float s0 = ftanh(wxv0[j] + b0);
      float s1 = ftanh(wxv1[j] + b1);
      float h0, h1;
      if (k == 0) { h0 = s0; h1 = s1; }
      else { h0 = ftanh(hb0[j] + s0); h1 = ftanh(hb1[j] + s1); }
      if (j < cnt) {
        hbuf[(size_t)idxs[j]*NH + lane]      = h0;  // final h for node i
        hbuf[(size_t)idxs[j]*NH + 64 + lane] = h1;
      }
      sh[wave][j][lane] = h0; sh[wave][j][64+lane] = h1;   // wave-synchronous LDS
    }
    float g0[4], g1[4];
    matvec4_g(wr0, wr1, sh[wave], g0, g1);           // g = W_hr . h
    #pragma unroll
    for (int j = 0; j < 4; j++) {                    // r = tanh(g + wx_parent)
      float r0 = ftanh(g0[j] + pw0[j]);
      float r1 = ftanh(g1[j] + pw1[j]);
      sh[wave][j][lane] = r0; sh[wave][j][64+lane] = r1;
    }
    float o0[4], o1[4];
    matvec4_g(re0, re1, sh[wave], o0, o1);           // infl = W_rel[t] . r
    #pragma unroll
    for (int j = 0; j < 4; j++) if (pidx[j] >= 0) {
      atomicAdd(&hbuf[(size_t)pidx[j]*NH + lane],      o0[j]);
      atomicAdd(&hbuf[(size_t)pidx[j]*NH + 64 + lane], o1[j]);
    }
  }
}

extern "C" void kernel_launch(void* const* d_in, const int* in_sizes, int n_in,
                              void* d_out, int out_size, void* d_ws, size_t ws_size,
                              hipStream_t stream) {
  const float* token  = (const float*)d_in[0];
  const float* Wwh    = (const float*)d_in[1];
  const float* bwh    = (const float*)d_in[2];
  const float* Whr    = (const float*)d_in[3];
  const float* Wrel   = (const float*)d_in[4];
  const int*   parent = (const int*)d_in[5];
  const int*   dep    = (const int*)d_in[6];
  const int*   height = (const int*)d_in[7];

  float* hbuf = (float*)d_out;                          // seg-accumulator, then final h
  float* wx   = (float*)d_ws;                           // [NN,NH] f32, 16MB
  int*   ib   = (int*)((char*)d_ws + 16777216);         // bucket metadata + node list

  count_kernel<<<CBLOCKS, 256, 0, stream>>>(dep, height, ib);
  scan_kernel<<<1, 128, 0, stream>>>(ib);
  scatter_kernel<<<CBLOCKS, 256, 0, stream>>>(dep, height, ib);
  wx_kernel<<<NN/64, 256, 0, stream>>>(token, Wwh, wx, hbuf);
  for (int k = 0; k < NLEVEL; k++)
    phase_kernel<<<PBLOCKS, 256, 0, stream>>>(Whr, Wrel, bwh, wx, parent, ib, hbuf, k);
}